// Round 13
// baseline (352.594 us; speedup 1.0000x reference)
//
#include <hip/hip_runtime.h>

namespace {
constexpr int B = 1024, Q = 128, P = 32, N = 128, D = 64, K = 160;

// ---------------- mean distance over cdist(x, y_pos) ----------------
__global__ __launch_bounds__(256) void k_meandist(
    const float* __restrict__ x, const float* __restrict__ y_pos,
    double* __restrict__ ws) {
  __shared__ float Yp[P][D];
  __shared__ float ysq[P];
  __shared__ float red[4];
  const int b = blockIdx.x, tid = threadIdx.x;
  const float* yb = y_pos + (size_t)b * P * D;
  for (int i = tid; i < P * D / 4; i += 256)
    reinterpret_cast<float4*>(&Yp[0][0])[i] = reinterpret_cast<const float4*>(yb)[i];
  __syncthreads();
  if (tid < P) {
    float s = 0.f;
    for (int d = 0; d < D; ++d) { float v = Yp[tid][d]; s = fmaf(v, v, s); }
    ysq[tid] = s;
  }
  __syncthreads();
  const int q = tid >> 1, ph = tid & 1;
  const float* xq = x + ((size_t)b * Q + q) * D;
  float acc[16];
#pragma unroll
  for (int j = 0; j < 16; ++j) acc[j] = 0.f;
  float xsq = 0.f;
#pragma unroll 1
  for (int d4 = 0; d4 < 16; ++d4) {
    float4 xv = reinterpret_cast<const float4*>(xq)[d4];
    xsq = fmaf(xv.x, xv.x, fmaf(xv.y, xv.y, fmaf(xv.z, xv.z, fmaf(xv.w, xv.w, xsq))));
#pragma unroll
    for (int j = 0; j < 16; ++j) {
      float4 yv = reinterpret_cast<const float4*>(&Yp[ph * 16 + j][0])[d4];
      acc[j] = fmaf(xv.x, yv.x, fmaf(xv.y, yv.y, fmaf(xv.z, yv.z, fmaf(xv.w, yv.w, acc[j]))));
    }
  }
  float dsum = 0.f;
#pragma unroll
  for (int j = 0; j < 16; ++j) {
    float d2 = xsq + ysq[ph * 16 + j] - 2.f * acc[j];
    dsum += sqrtf(fmaxf(d2, 0.f));
  }
#pragma unroll
  for (int m = 1; m < 64; m <<= 1) dsum += __shfl_xor(dsum, m);
  if ((tid & 63) == 0) red[tid >> 6] = dsum;
  __syncthreads();
  if (tid == 0)
    atomicAdd(ws, (double)(red[0] + red[1] + red[2] + red[3]));
}

// ------------- fused drift: 1024 thr = TWO independent 512-thr halves ------
// Occupancy ledger (R5-R12): runtime never co-schedules a 2nd workgroup
// beyond the waves_per_eu MIN (R6: min=4 packed 2x512 but budget->64->spill).
// Ceiling = 16 waves/CU via one 1024-thr block. Ledger also shows per-thread
// tile size beats wave count (R5 8q-tiles @8 waves: 208us > R11/R12 4q-tiles
// @16 waves: 245-258us). So: two batches per block, each half runs the
// PROVEN R10 phases (dist zz[8][5] @76 VGPR, k_gemm dr[4][8]) with slab-C.
// LDS 2x17440f + redd = 139.6KB <= 160KB. waves_per_eu(2,4): 128 budget.
__global__
__attribute__((amdgpu_flat_work_group_size(1024, 1024)))
__attribute__((amdgpu_waves_per_eu(2, 4)))
void k_drift5(
    const float* __restrict__ x, const float* __restrict__ y_pos,
    const float* __restrict__ y_neg, double* __restrict__ ws) {
  // Per-half LDS map (floats, stride HS=17440):
  //  [0,10240)      Y4 [160][16] f4 row-rotated by k (reused as merge buf)
  //  [10240,15520)  union: X chunk [128][8] f4 (4096 f) / C slab [40][33] f4
  //  [15520,15904)  rss [3][128]
  //  [15904,16384)  css [3][160] -> rsqrt in place
  //  [16384,16768)  uss [3][128] -> /rs   (sum over pos k)
  //  [16768,17152)  vss [3][128] -> /rs   (sum over neg k)
  //  [17152,17312)  ysq [160];  [17312,17440) pad
  // Shared tail: redd 8 doubles.
  constexpr int HS = 17440;
  __shared__ __align__(16) float SM[2 * HS + 16];
  const int tid = threadIdx.x;
  const int h = tid >> 9, ltid = tid & 511;
  float* HB = SM + h * HS;
  float4* Y4  = (float4*)HB;
  float4* XC  = (float4*)(HB + 10240);
  float4* C4s = XC;
  float* rss = HB + 15520;
  float* css = HB + 15904;
  float* uss = HB + 16384;
  float* vss = HB + 16768;
  float* ysq = HB + 17152;
  double* redd = (double*)(SM + 2 * HS);

  const int b = blockIdx.x * 2 + h;
  const float4* yn4 = (const float4*)(y_neg + (size_t)b * N * D);
  const float4* yp4 = (const float4*)(y_pos + (size_t)b * P * D);
  const float4* xg  = (const float4*)(x + (size_t)b * Q * D);

  // ---- stage Y (rotated) + zero sums ----
  for (int idx = ltid; idx < K * 16; idx += 512) {
    int k = idx >> 4, d4 = idx & 15;
    float4 v = (k < N) ? yn4[k * 16 + d4] : yp4[(k - N) * 16 + d4];
    Y4[k * 16 + ((d4 + k) & 15)] = v;
  }
  if (ltid < 384) { rss[ltid] = 0.f; uss[ltid] = 0.f; vss[ltid] = 0.f; }
  __syncthreads();
  if (ltid < K) {
    float s = 0.f;
#pragma unroll
    for (int c = 0; c < 16; ++c) {
      float4 v = Y4[ltid * 16 + ((c + ltid) & 15)];
      s = fmaf(v.x, v.x, fmaf(v.y, v.y, fmaf(v.z, v.z, fmaf(v.w, v.w, s))));
    }
    ysq[ltid] = s;
  }

  // producer mapping (R10-proven): qg = ltid&15 -> q in [8qg,8qg+8);
  // kt = ltid>>4 (0..31); k = kt+32j (j=0..4; j==4 <=> pos)
  const int qg = ltid & 15, kt = ltid >> 4;
  const int qb = qg * 8;

  float zz[8][5];
  float xsq8[8];
#pragma unroll
  for (int i = 0; i < 8; ++i) {
    xsq8[i] = 0.f;
#pragma unroll
    for (int j = 0; j < 5; ++j) zz[i][j] = 0.f;
  }

  // ---- dist phase (R10's exact register discipline: 76 VGPR, no spill) ----
#pragma unroll 1
  for (int ch = 0; ch < 2; ++ch) {
    __syncthreads();
#pragma unroll
    for (int r = 0; r < 2; ++r) {
      int idx = ltid + 512 * r;
      int q = idx >> 3, c = idx & 7;
      XC[q * 8 + ((c + (q >> 3)) & 7)] = xg[q * 16 + ch * 8 + c];
    }
    __syncthreads();
#pragma unroll 2
    for (int d4 = 0; d4 < 8; ++d4) {
      const int gd4 = ch * 8 + d4;
      float4 yv[5];
#pragma unroll
      for (int j = 0; j < 5; ++j) {
        const int k_ = kt + 32 * j;
        yv[j] = Y4[k_ * 16 + ((gd4 + k_) & 15)];
      }
      const int rx = (d4 + qg) & 7;
#pragma unroll
      for (int i = 0; i < 8; ++i) {
        float4 xv = XC[(qb + i) * 8 + rx];
        xsq8[i] = fmaf(xv.x, xv.x, fmaf(xv.y, xv.y,
                  fmaf(xv.z, xv.z, fmaf(xv.w, xv.w, xsq8[i]))));
#pragma unroll
        for (int j = 0; j < 5; ++j)
          zz[i][j] = fmaf(xv.x, yv[j].x, fmaf(xv.y, yv[j].y,
                     fmaf(xv.z, yv[j].z, fmaf(xv.w, yv[j].w, zz[i][j]))));
      }
    }
  }
  const float meand = (float)(ws[0] * (1.0 / ((double)B * Q * P)));
  const float invt2 = 1.0f / fmaxf(meand, 1e-6f);
#pragma unroll
  for (int i = 0; i < 8; ++i)
#pragma unroll
    for (int j = 0; j < 5; ++j) {
      const int k_ = kt + 32 * j;
      float d2 = xsq8[i] + ysq[k_] - 2.f * zz[i][j];
      zz[i][j] = __expf(-sqrtf(fmaxf(d2, 0.f)) * invt2);
    }

  // ---- pass 1: row sums (rss) / col sums (css) per temp ----
#pragma unroll
  for (int t = 0; t < 3; ++t) {
    float ers[8] = {0.f,0.f,0.f,0.f,0.f,0.f,0.f,0.f};
    float ecs[5] = {0.f,0.f,0.f,0.f,0.f};
#pragma unroll
    for (int i = 0; i < 8; ++i)
#pragma unroll
      for (int j = 0; j < 5; ++j) {
        float z = zz[i][j], f;
        if (t == 2) f = z;
        else if (t == 1) f = z * z;
        else { float z2 = z * z, z4 = z2 * z2; f = z4 * z4 * z2; }
        ers[i] += f; ecs[j] += f;
      }
#pragma unroll
    for (int j = 0; j < 5; ++j) {
      float v = ecs[j];
      v += __shfl_xor(v, 1); v += __shfl_xor(v, 2);
      v += __shfl_xor(v, 4); v += __shfl_xor(v, 8);
      if (qg == 0) css[t * 160 + kt + 32 * j] = v;
    }
#pragma unroll
    for (int i = 0; i < 8; ++i) {
      float v = ers[i];
      v += __shfl_xor(v, 16); v += __shfl_xor(v, 32);
      if ((kt & 3) == 0) atomicAdd(&rss[t * 128 + qb + i], v);
    }
  }
  __syncthreads();
  if (ltid < 480) css[ltid] = rsqrtf(css[ltid]);
  __syncthreads();

  // ---- pass 2: sum_pos (uss) / sum_neg (vss) of e*ics per (temp, q) ----
#pragma unroll
  for (int t = 0; t < 3; ++t) {
    float icr[5];
#pragma unroll
    for (int j = 0; j < 5; ++j) icr[j] = css[t * 160 + kt + 32 * j];
    float uu[8] = {0.f,0.f,0.f,0.f,0.f,0.f,0.f,0.f};
    float vv[8] = {0.f,0.f,0.f,0.f,0.f,0.f,0.f,0.f};
#pragma unroll
    for (int i = 0; i < 8; ++i)
#pragma unroll
      for (int j = 0; j < 5; ++j) {
        float z = zz[i][j], f;
        if (t == 2) f = z;
        else if (t == 1) f = z * z;
        else { float z2 = z * z, z4 = z2 * z2; f = z4 * z4 * z2; }
        float a = f * icr[j];
        if (j == 4) uu[i] += a; else vv[i] += a;
      }
#pragma unroll
    for (int i = 0; i < 8; ++i) {
      float u = uu[i];
      u += __shfl_xor(u, 16); u += __shfl_xor(u, 32);
      float v = vv[i];
      v += __shfl_xor(v, 16); v += __shfl_xor(v, 32);
      if ((kt & 3) == 0) {
        atomicAdd(&uss[t * 128 + qb + i], u);
        atomicAdd(&vss[t * 128 + qb + i], v);
      }
    }
  }
  __syncthreads();
  if (ltid < 384) {
    float inv = 1.0f / rss[ltid];
    uss[ltid] *= inv;
    vss[ltid] *= inv;
  }

  // ---- 4 slabs: produce combined coefficients (40 k), consume as GEMM ----
  // consumer (R10 k_gemm-proven): kc = ltid>>8, qc = (ltid>>3)&31, dc = ltid&7
  const int kc = ltid >> 8, qc = (ltid >> 3) & 31, dc = ltid & 7;
  float dr[4][8];
#pragma unroll
  for (int i = 0; i < 4; ++i)
#pragma unroll
    for (int n = 0; n < 8; ++n) dr[i][n] = 0.f;

#pragma unroll 1
  for (int s = 0; s < 4; ++s) {
    __syncthreads();    // slab buffer free (s=0: also covers uss/vss scaling)
#pragma unroll
    for (int j = 0; j < 5; ++j) {
      const int klocal = kt + 32 * j - 40 * s;
      if (klocal >= 0 && klocal < 40) {
        const int k_ = kt + 32 * j;
        const bool pos = (j == 4);
        const float ic0 = css[k_], ic1 = css[160 + k_], ic2 = css[320 + k_];
        float c0a[8];
#pragma unroll
        for (int i = 0; i < 8; ++i) {
          const int q2 = qb + i;
          float a0 = pos ? vss[q2]       : uss[q2];
          float a1 = pos ? vss[128 + q2] : uss[128 + q2];
          float a2 = pos ? vss[256 + q2] : uss[256 + q2];
          float z = zz[i][j], z2 = z * z, z4 = z2 * z2, z10 = z4 * z4 * z2;
          float c = fmaf(z, ic2 * a2, fmaf(z2, ic1 * a1, z10 * (ic0 * a0)));
          c0a[i] = pos ? c : -c;
        }
        C4s[klocal * 33 + 2 * qg]     = make_float4(c0a[0], c0a[1], c0a[2], c0a[3]);
        C4s[klocal * 33 + 2 * qg + 1] = make_float4(c0a[4], c0a[5], c0a[6], c0a[7]);
      }
    }
    __syncthreads();
#pragma unroll 2
    for (int kl = 0; kl < 20; ++kl) {
      const int klocal = kc * 20 + kl;
      const int k_ = 40 * s + klocal;
      float4 ca = C4s[klocal * 33 + qc];
      float4 y0 = Y4[k_ * 16 + ((2 * dc + k_) & 15)];
      float4 y1 = Y4[k_ * 16 + ((2 * dc + 1 + k_) & 15)];
#define GACC(ii, cv)                               \
      dr[ii][0] = fmaf(cv, y0.x, dr[ii][0]);       \
      dr[ii][1] = fmaf(cv, y0.y, dr[ii][1]);       \
      dr[ii][2] = fmaf(cv, y0.z, dr[ii][2]);       \
      dr[ii][3] = fmaf(cv, y0.w, dr[ii][3]);       \
      dr[ii][4] = fmaf(cv, y1.x, dr[ii][4]);       \
      dr[ii][5] = fmaf(cv, y1.y, dr[ii][5]);       \
      dr[ii][6] = fmaf(cv, y1.z, dr[ii][6]);       \
      dr[ii][7] = fmaf(cv, y1.w, dr[ii][7]);
      GACC(0, ca.x) GACC(1, ca.y) GACC(2, ca.z) GACC(3, ca.w)
#undef GACC
    }
  }
  __syncthreads();   // all GEMM reads of Y done -> Y reusable as merge buf

  // ---- merge kc halves (freed Y region) + loss (R10 k_gemm-proven) ----
  float4* FB = Y4;
  if (kc == 1) {
#pragma unroll
    for (int i = 0; i < 4; ++i) {
      const int q = qc * 4 + i;
#pragma unroll
      for (int w = 0; w < 2; ++w)
        FB[q * 16 + ((2 * dc + w + q) & 15)] =
            make_float4(dr[i][w*4], dr[i][w*4+1], dr[i][w*4+2], dr[i][w*4+3]);
    }
  }
  __syncthreads();
  if (kc == 0) {
    float tot = 0.f;
#pragma unroll
    for (int i = 0; i < 4; ++i) {
      const int q = qc * 4 + i;
#pragma unroll
      for (int w = 0; w < 2; ++w) {
        float4 v = FB[q * 16 + ((2 * dc + w + q) & 15)];
        float a0 = dr[i][w*4]   + v.x;
        float a1 = dr[i][w*4+1] + v.y;
        float a2 = dr[i][w*4+2] + v.z;
        float a3 = dr[i][w*4+3] + v.w;
        tot = fmaf(a0, a0, tot); tot = fmaf(a1, a1, tot);
        tot = fmaf(a2, a2, tot); tot = fmaf(a3, a3, tot);
      }
    }
#pragma unroll
    for (int m = 1; m < 64; m <<= 1) tot += __shfl_xor(tot, m);
    if ((ltid & 63) == 0) redd[h * 4 + (ltid >> 6)] = (double)tot;  // 8 slots
  }
  __syncthreads();
  if (tid == 0) {
    double sT = 0.0;
#pragma unroll
    for (int w = 0; w < 8; ++w) sT += redd[w];
    atomicAdd(ws + 1, sT);
  }
}

__global__ void k_final(const double* __restrict__ ws, float* __restrict__ out) {
  out[0] = (float)(ws[1] / ((double)B * Q * D));
}

}  // namespace

extern "C" void kernel_launch(void* const* d_in, const int* in_sizes, int n_in,
                              void* d_out, int out_size, void* d_ws, size_t ws_size,
                              hipStream_t stream) {
  const float* x = (const float*)d_in[0];
  const float* y_pos = (const float*)d_in[1];
  const float* y_neg = (const float*)d_in[2];
  float* out = (float*)d_out;
  double* ws = (double*)d_ws;

  hipMemsetAsync(d_ws, 0, 2 * sizeof(double), stream);
  k_meandist<<<B, 256, 0, stream>>>(x, y_pos, ws);
  k_drift5<<<B / 2, 1024, 0, stream>>>(x, y_pos, y_neg, ws);
  k_final<<<1, 1, 0, stream>>>(ws, out);
}